// Round 2
// baseline (317.592 us; speedup 1.0000x reference)
//
#include <hip/hip_runtime.h>
#include <math.h>

// Sparse implementation of the masked 3D CNN (B=2, S=128, N=60000 points).
// Levels: 0:128^3  1:64^3  2:32^3  3:16^3  4:8^3, then dense pools 4^3, 2^3.
// uint16 index grids (ids < 60000; 0xFFFF empty, 0xFFFE marked), block-scan
// compaction, BN stats fused into producer kernels, BN-apply fused into
// consumer convs.

#define NPTS 60000
#define NB 2
#define NEGF -3.0e38f
#define EPSF 1.0e-4f
#define MARKV 0xFFFEu
#define EMPTYV 0xFFFFu

constexpr int NV0 = NB * 128 * 128 * 128;  // 4194304
constexpr int NV1 = NB * 64 * 64 * 64;     // 524288
constexpr int NV2 = NB * 32 * 32 * 32;     // 65536
constexpr int NV3 = NB * 16 * 16 * 16;     // 8192
constexpr int NV4 = NB * 8 * 8 * 8;        // 1024

// ---- workspace layout (bytes) ----
constexpr size_t OFF_CNT   = 0;     // int[16]
constexpr size_t OFF_BNSUM = 64;    // float[4][64]
constexpr size_t OFF_BNSS  = 1088;  // float[4][64]
constexpr size_t OFF_MASK5 = 2112;  // int[128]
constexpr size_t OFF_FGRID = 4096;                        // float[NV0]
constexpr size_t OFF_IDX0  = OFF_FGRID + (size_t)NV0 * 4; // u16[NV0]
constexpr size_t OFF_IDX1  = OFF_IDX0 + (size_t)NV0 * 2;
constexpr size_t OFF_IDX2  = OFF_IDX1 + (size_t)NV1 * 2;
constexpr size_t OFF_IDX3  = OFF_IDX2 + (size_t)NV2 * 2;
constexpr size_t OFF_IDX4  = OFF_IDX3 + (size_t)NV3 * 2;  // contiguous after idx3
constexpr size_t OFF_LIST0 = OFF_IDX4 + (size_t)NV4 * 2;
constexpr size_t OFF_LIST1 = OFF_LIST0 + (size_t)NPTS * 4;
constexpr size_t OFF_LIST2 = OFF_LIST1 + (size_t)NPTS * 4;
constexpr size_t OFF_LIST3 = OFF_LIST2 + (size_t)NPTS * 4;
constexpr size_t OFF_LIST4 = OFF_LIST3 + (size_t)NV3 * 4;
constexpr size_t OFF_H0 = OFF_LIST4 + (size_t)NV4 * 4;    // NPTS*8  f32
constexpr size_t OFF_H1 = OFF_H0 + (size_t)NPTS * 8 * 4;  // NPTS*16
constexpr size_t OFF_H2 = OFF_H1 + (size_t)NPTS * 16 * 4; // NPTS*32
constexpr size_t OFF_H3 = OFF_H2 + (size_t)NPTS * 32 * 4; // NV3*64
constexpr size_t OFF_H4 = OFF_H3 + (size_t)NV3 * 64 * 4;  // dense [b][128][8^3]
constexpr size_t OFF_H5 = OFF_H4 + (size_t)NV4 * 128 * 4; // [b][128][4^3]
constexpr size_t WS_END = OFF_H5 + (size_t)NB * 128 * 64 * 4;  // ~43.3 MB

// ---------------- kernels ----------------

// scatter points; also clears cnt/bn (528 words) and idx1 (NV1 u16).
__global__ __launch_bounds__(256) void k_scatter(const float* __restrict__ pc,
                                                 float* __restrict__ fgrid,
                                                 unsigned short* __restrict__ idx0,
                                                 unsigned short* __restrict__ idx1,
                                                 int* __restrict__ wsw,
                                                 float* __restrict__ out) {
  int gid = blockIdx.x * 256 + threadIdx.x;  // grid = NV1 threads
  if (gid < 528) wsw[gid] = 0;
  idx1[gid] = (unsigned short)EMPTYV;
  if (gid < NPTS) {
    const float* p = pc + (size_t)gid * 5;
    float fb = p[0], fx = p[1], fy = p[2], fz = p[3], f = p[4];
    ((float4*)out)[gid] = make_float4(fb, fx, fy, fz);
    int b = (int)fb, x = (int)fx, y = (int)fy, z = (int)fz;
    int v = ((b * 128 + x) * 128 + y) * 128 + z;
    atomicAdd(&fgrid[v], f);
    idx0[v] = (unsigned short)MARKV;  // benign multi-writer (same value)
  }
}

// block-scan compaction: 4 voxels/thread, wave prefix-scan, 1 global atomic
// per block. Marks parent level; optionally clears another u16/f32 region.
template <int SL, int NCLR16, int NCLRF>
__global__ __launch_bounds__(256) void k_cscan(unsigned short* __restrict__ idx,
                                               int* __restrict__ list,
                                               int* __restrict__ cnt, int slot,
                                               unsigned short* __restrict__ idx_par,
                                               unsigned short* __restrict__ clr16,
                                               float* __restrict__ clrf) {
  constexpr int NV = NB * SL * SL * SL;
  constexpr int NT = NV / 4;  // total threads
  int gid = blockIdx.x * 256 + threadIdx.x;
  if (NCLR16 > 0 && gid < NCLR16) clr16[gid] = (unsigned short)EMPTYV;
  if (NCLRF > 0) {
    float4 z4 = make_float4(0.f, 0.f, 0.f, 0.f);
    for (int i = gid; i < NCLRF / 4; i += NT) ((float4*)clrf)[i] = z4;
  }
  ushort4 u = ((const ushort4*)idx)[gid];
  int p0 = (u.x == MARKV), p1 = (u.y == MARKV), p2 = (u.z == MARKV), p3 = (u.w == MARKV);
  int c = p0 + p1 + p2 + p3;
  int lane = threadIdx.x & 63, wid = threadIdx.x >> 6;
  int x = c;
#pragma unroll
  for (int off = 1; off < 64; off <<= 1) {  // inclusive wave scan
    int y = __shfl_up(x, off, 64);
    if (lane >= off) x += y;
  }
  __shared__ int sw[4];
  __shared__ int sbase;
  if (lane == 63) sw[wid] = x;
  __syncthreads();
  if (threadIdx.x == 0) {
    int r = 0;
#pragma unroll
    for (int w = 0; w < 4; w++) { int t = sw[w]; sw[w] = r; r += t; }
    sbase = r ? atomicAdd(&cnt[slot], r) : 0;
  }
  __syncthreads();
  if (!c) return;
  int my = sbase + sw[wid] + (x - c);
  int v0 = gid * 4;
  int pr[4] = {p0, p1, p2, p3};
#pragma unroll
  for (int j = 0; j < 4; j++) {
    if (pr[j]) {
      int v = v0 + j;
      idx[v] = (unsigned short)my;
      list[my] = v;
      my++;
      int z = v & (SL - 1), y = (v / SL) & (SL - 1),
          xx = (v / (SL * SL)) & (SL - 1), b = v / (SL * SL * SL);
      constexpr int SP = SL / 2;
      int pv = ((b * SP + (xx >> 1)) * SP + (y >> 1)) * SP + (z >> 1);
      idx_par[pv] = (unsigned short)MARKV;
    }
  }
}

// levels 3 and 4 compaction in one single-block kernel.
__global__ __launch_bounds__(256) void k_ctail(unsigned short* __restrict__ idx3,
                                               unsigned short* __restrict__ idx4,
                                               int* __restrict__ list3,
                                               int* __restrict__ list4,
                                               int* __restrict__ cnt) {
  __shared__ int lc3, lc4;
  int tid = threadIdx.x, lane = tid & 63;
  if (tid == 0) { lc3 = 0; lc4 = 0; }
  __syncthreads();
  for (int v = tid; v < NV3; v += 256) {
    bool p = (idx3[v] == MARKV);
    unsigned long long m = __ballot(p);
    int wb = 0;
    if (lane == 0 && m) wb = atomicAdd(&lc3, __popcll(m));
    wb = __shfl(wb, 0, 64);
    if (p) {
      int id = wb + __popcll(m & ((1ull << lane) - 1));
      idx3[v] = (unsigned short)id;
      list3[id] = v;
      int z = v & 15, y = (v >> 4) & 15, x = (v >> 8) & 15, b = v >> 12;
      int pv = ((b * 8 + (x >> 1)) * 8 + (y >> 1)) * 8 + (z >> 1);
      idx4[pv] = (unsigned short)MARKV;
    }
  }
  __syncthreads();  // idx4 marks visible block-wide
  for (int v = tid; v < NV4; v += 256) {
    bool p = (idx4[v] == MARKV);
    unsigned long long m = __ballot(p);
    int wb = 0;
    if (lane == 0 && m) wb = atomicAdd(&lc4, __popcll(m));
    wb = __shfl(wb, 0, 64);
    if (p) {
      int id = wb + __popcll(m & ((1ull << lane) - 1));
      idx4[v] = (unsigned short)id;
      list4[id] = v;
    }
  }
  __syncthreads();
  if (tid == 0) { cnt[3] = lc3; cnt[4] = lc4; }
}

// 3^3 SAME conv 1->8 at occupied voxels; fused BN0 stat accumulation.
__global__ __launch_bounds__(256) void k_subconv(const float* __restrict__ fgrid,
                                                 const int* __restrict__ list0,
                                                 const int* __restrict__ cnt,
                                                 const float* __restrict__ wsub,
                                                 float* __restrict__ h0,
                                                 float* __restrict__ bnsum,
                                                 float* __restrict__ bnss) {
  int n = cnt[0];
  if ((int)(blockIdx.x * 256) >= n) return;  // uniform
  __shared__ float wl[216];
  __shared__ float sbn[16];
  int tid = threadIdx.x;
  for (int i = tid; i < 216; i += 256) wl[i] = wsub[i];
  if (tid < 16) sbn[tid] = 0.f;
  __syncthreads();
  int id = blockIdx.x * 256 + tid;
  bool act = id < n;
  float acc[8] = {0, 0, 0, 0, 0, 0, 0, 0};
  if (act) {
    int v = list0[id];
    int z = v & 127, y = (v >> 7) & 127, x = (v >> 14) & 127, b = v >> 21;
    for (int kd = 0; kd < 3; kd++) {
      int xx = x + kd - 1;
      if ((unsigned)xx >= 128u) continue;
      for (int kh = 0; kh < 3; kh++) {
        int yy = y + kh - 1;
        if ((unsigned)yy >= 128u) continue;
        for (int kw = 0; kw < 3; kw++) {
          int zz = z + kw - 1;
          if ((unsigned)zz >= 128u) continue;
          float val = fgrid[((b * 128 + xx) * 128 + yy) * 128 + zz];
          if (val != 0.f) {  // exact: contribution is val*w
            int t = (kd * 3 + kh) * 3 + kw;
#pragma unroll
            for (int o = 0; o < 8; o++) acc[o] = fmaf(val, wl[o * 27 + t], acc[o]);
          }
        }
      }
    }
#pragma unroll
    for (int o = 0; o < 8; o++) h0[(size_t)id * 8 + o] = acc[o];
  }
  int lane = tid & 63;
#pragma unroll
  for (int o = 0; o < 8; o++) {
    float a = acc[o], q = a * a;
#pragma unroll
    for (int off = 32; off > 0; off >>= 1) {
      a += __shfl_down(a, off, 64);
      q += __shfl_down(q, off, 64);
    }
    if (lane == 0) { atomicAdd(&sbn[o], a); atomicAdd(&sbn[8 + o], q); }
  }
  __syncthreads();
  if (tid < 8) { atomicAdd(&bnsum[tid], sbn[tid]); atomicAdd(&bnss[tid], sbn[8 + tid]); }
}

// stride-2 VALID 2^3 conv. BN+ReLU applied to inputs (scale/bias derived
// in-block from fused stats); output BN stats accumulated unless DENSE_OUT.
template <int Ci, int Co, int OCCHUNK, int SLpar, int DENSE_OUT>
__global__ __launch_bounds__(256) void k_conv(const float* __restrict__ hin,
                                              const unsigned short* __restrict__ idxc,
                                              const int* __restrict__ listpar,
                                              const int* __restrict__ cnt,
                                              int slot_bn, int slot_par,
                                              const float* __restrict__ w,
                                              const float* __restrict__ bnsum_in,
                                              const float* __restrict__ bnss_in,
                                              const float* __restrict__ g,
                                              const float* __restrict__ beta,
                                              float* __restrict__ bnsum_out,
                                              float* __restrict__ bnss_out,
                                              float* __restrict__ hout) {
  constexpr int TPP = OCCHUNK / 8;   // threads per parent
  constexpr int PPB = 256 / TPP;     // parents per block
  int n = cnt[slot_par];
  if ((int)(blockIdx.x * PPB) >= n) return;  // uniform
  __shared__ float wl[Ci * 8 * OCCHUNK];     // <= 32 KB for all stages
  __shared__ float sl[Ci], bl[Ci];
  __shared__ float bnl[2 * OCCHUNK];
  int tid = threadIdx.x;
  int ocbase = blockIdx.y * OCCHUNK;
  for (int i = tid; i < Ci * 8 * OCCHUNK; i += 256) {
    int ol = i % OCCHUNK;
    int it = i / OCCHUNK;  // ci*8 + t
    int ci = it >> 3, t = it & 7;
    wl[i] = w[((size_t)(ocbase + ol) * Ci + ci) * 8 + t];
  }
  if (tid < Ci) {
    float nn = (float)cnt[slot_bn];
    float mu = bnsum_in[tid] / nn;
    float var = bnss_in[tid] / nn - mu * mu;
    var = fmaxf(var, 0.f);
    float sc = g[tid] / sqrtf(var + EPSF);
    sl[tid] = sc;
    bl[tid] = beta[tid] - mu * sc;
  }
  if (!DENSE_OUT && tid < 2 * OCCHUNK) bnl[tid] = 0.f;
  __syncthreads();
  int pid = blockIdx.x * PPB + tid / TPP;
  int og = tid % TPP;
  bool act = pid < n;
  float acc[8] = {0, 0, 0, 0, 0, 0, 0, 0};
  int Xc = 0, Yc = 0, Zc = 0, bb = 0;
  if (act) {
    int pv = listpar[pid];
    constexpr int SL = SLpar, SC = SLpar * 2;
    Zc = pv & (SL - 1);
    Yc = (pv / SL) & (SL - 1);
    Xc = (pv / (SL * SL)) & (SL - 1);
    bb = pv / (SL * SL * SL);
    for (int t = 0; t < 8; t++) {
      int kd = t >> 2, kh = (t >> 1) & 1, kw = t & 1;
      int cv = ((bb * SC + 2 * Xc + kd) * SC + 2 * Yc + kh) * SC + 2 * Zc + kw;
      unsigned e = idxc[cv];
      if (e >= 0xFFFEu) continue;  // empty child contributes 0
      const float* hp = hin + (size_t)e * Ci;
#pragma unroll
      for (int i = 0; i < Ci; i += 4) {
        float4 xv = *(const float4*)(hp + i);
        float y0 = fmaxf(fmaf(xv.x, sl[i + 0], bl[i + 0]), 0.f);
        float y1 = fmaxf(fmaf(xv.y, sl[i + 1], bl[i + 1]), 0.f);
        float y2 = fmaxf(fmaf(xv.z, sl[i + 2], bl[i + 2]), 0.f);
        float y3 = fmaxf(fmaf(xv.w, sl[i + 3], bl[i + 3]), 0.f);
        const float* wp0 = &wl[((i + 0) * 8 + t) * OCCHUNK + og * 8];
        const float* wp1 = &wl[((i + 1) * 8 + t) * OCCHUNK + og * 8];
        const float* wp2 = &wl[((i + 2) * 8 + t) * OCCHUNK + og * 8];
        const float* wp3 = &wl[((i + 3) * 8 + t) * OCCHUNK + og * 8];
#pragma unroll
        for (int o = 0; o < 8; o++) {
          acc[o] = fmaf(y0, wp0[o], acc[o]);
          acc[o] = fmaf(y1, wp1[o], acc[o]);
          acc[o] = fmaf(y2, wp2[o], acc[o]);
          acc[o] = fmaf(y3, wp3[o], acc[o]);
        }
      }
    }
    if (!DENSE_OUT) {
      float* op = hout + (size_t)pid * Co + ocbase + og * 8;
#pragma unroll
      for (int o = 0; o < 8; o++) op[o] = acc[o];
    } else {
      int sp = (Xc * 8 + Yc) * 8 + Zc;  // SLpar == 8
#pragma unroll
      for (int o = 0; o < 8; o++)
        hout[((size_t)bb * 128 + ocbase + og * 8 + o) * 512 + sp] = acc[o];
    }
  }
  if (!DENSE_OUT) {
    int lane = tid & 63;
#pragma unroll
    for (int o = 0; o < 8; o++) {
      float a = acc[o], q = a * a;
#pragma unroll
      for (int off = TPP; off < 64; off <<= 1) {
        a += __shfl_down(a, off, 64);
        q += __shfl_down(q, off, 64);
      }
      if (lane < TPP) {  // og == lane here
        atomicAdd(&bnl[lane * 8 + o], a);
        atomicAdd(&bnl[OCCHUNK + lane * 8 + o], q);
      }
    }
    __syncthreads();
    if (tid < OCCHUNK) {
      atomicAdd(&bnsum_out[ocbase + tid], bnl[tid]);
      atomicAdd(&bnss_out[ocbase + tid], bnl[OCCHUNK + tid]);
    }
  }
}

// masked max-pool 8^3 -> 4^3 (dense), emits mask5.
__global__ __launch_bounds__(256) void k_pool1(const float* __restrict__ h4,
                                               const unsigned short* __restrict__ idx4,
                                               float* __restrict__ h5,
                                               int* __restrict__ mask5) {
  int tid = blockIdx.x * 256 + threadIdx.x;  // exactly NB*128*64 threads
  int sp = tid & 63;
  int c = (tid >> 6) & 127;
  int b = tid >> 13;
  int Z = sp & 3, Y = (sp >> 2) & 3, X = sp >> 4;
  float m = NEGF;
  int any = 0;
#pragma unroll
  for (int t = 0; t < 8; t++) {
    int kd = t >> 2, kh = (t >> 1) & 1, kw = t & 1;
    int csp = ((2 * X + kd) * 8 + 2 * Y + kh) * 8 + 2 * Z + kw;
    if (idx4[b * 512 + csp] != EMPTYV) {
      any = 1;
      m = fmaxf(m, h4[((size_t)b * 128 + c) * 512 + csp]);
    }
  }
  h5[((size_t)b * 128 + c) * 64 + sp] = any ? m : 0.f;
  if (c == 0) mask5[b * 64 + sp] = any;
}

// fused: masked max-pool 4^3 -> 2^3 + ReLU + (2x1024) linear classifier.
__global__ __launch_bounds__(256) void k_tail(const float* __restrict__ h5,
                                              const int* __restrict__ mask5,
                                              const float* __restrict__ Wc,
                                              const float* __restrict__ bcv,
                                              float* __restrict__ out) {
  __shared__ float h6s[2048];
  int tid = threadIdx.x;
#pragma unroll
  for (int j = 0; j < 8; j++) {
    int e = tid * 8 + j;  // e = b*1024 + c*8 + sp
    int sp = e & 7, c = (e >> 3) & 127, b = e >> 10;
    int Z = sp & 1, Y = (sp >> 1) & 1, X = sp >> 2;
    float m = NEGF;
    int any = 0;
#pragma unroll
    for (int t = 0; t < 8; t++) {
      int kd = t >> 2, kh = (t >> 1) & 1, kw = t & 1;
      int csp = ((2 * X + kd) * 4 + 2 * Y + kh) * 4 + 2 * Z + kw;
      if (mask5[b * 64 + csp]) {
        any = 1;
        m = fmaxf(m, h5[((size_t)b * 128 + c) * 64 + csp]);
      }
    }
    h6s[e] = any ? fmaxf(m, 0.f) : 0.f;  // classifier ReLU folded in
  }
  __syncthreads();
  int wave = tid >> 6, lane = tid & 63;
  int b = wave >> 1, o = wave & 1;
  float s = 0.f;
  for (int k = lane; k < 1024; k += 64) s += h6s[b * 1024 + k] * Wc[o * 1024 + k];
#pragma unroll
  for (int off = 32; off > 0; off >>= 1) s += __shfl_down(s, off, 64);
  if (lane == 0) out[240000 + b * 2 + o] = s + bcv[o];
}

// ---------------- host ----------------

extern "C" void kernel_launch(void* const* d_in, const int* in_sizes, int n_in,
                              void* d_out, int out_size, void* d_ws, size_t ws_size,
                              hipStream_t stream) {
  const float* pc   = (const float*)d_in[0];
  const float* wsub = (const float*)d_in[1];
  const float* w0   = (const float*)d_in[2];
  const float* w1   = (const float*)d_in[3];
  const float* w2   = (const float*)d_in[4];
  const float* w3   = (const float*)d_in[5];
  const float* g0   = (const float*)d_in[6];
  const float* g1   = (const float*)d_in[7];
  const float* g2   = (const float*)d_in[8];
  const float* g3   = (const float*)d_in[9];
  const float* b0   = (const float*)d_in[10];
  const float* b1   = (const float*)d_in[11];
  const float* b2   = (const float*)d_in[12];
  const float* b3   = (const float*)d_in[13];
  const float* Wc   = (const float*)d_in[14];
  const float* bc   = (const float*)d_in[15];
  float* out = (float*)d_out;

  char* base = (char*)d_ws;
  int*   cnt   = (int*)(base + OFF_CNT);
  float* bnsum = (float*)(base + OFF_BNSUM);  // [4][64]
  float* bnss  = (float*)(base + OFF_BNSS);   // [4][64]
  int*   mask5 = (int*)(base + OFF_MASK5);
  float* fgrid = (float*)(base + OFF_FGRID);
  unsigned short* idx0 = (unsigned short*)(base + OFF_IDX0);
  unsigned short* idx1 = (unsigned short*)(base + OFF_IDX1);
  unsigned short* idx2 = (unsigned short*)(base + OFF_IDX2);
  unsigned short* idx3 = (unsigned short*)(base + OFF_IDX3);
  unsigned short* idx4 = (unsigned short*)(base + OFF_IDX4);
  int* list0 = (int*)(base + OFF_LIST0);
  int* list1 = (int*)(base + OFF_LIST1);
  int* list2 = (int*)(base + OFF_LIST2);
  int* list3 = (int*)(base + OFF_LIST3);
  int* list4 = (int*)(base + OFF_LIST4);
  float* h0 = (float*)(base + OFF_H0);
  float* h1 = (float*)(base + OFF_H1);
  float* h2 = (float*)(base + OFF_H2);
  float* h3 = (float*)(base + OFF_H3);
  float* h4 = (float*)(base + OFF_H4);
  float* h5 = (float*)(base + OFF_H5);

  hipMemsetAsync(fgrid, 0, (size_t)NV0 * 4, stream);
  hipMemsetAsync(idx0, 0xFF, (size_t)NV0 * 2, stream);

  // scatter (+ clear cnt/bn, idx1)
  k_scatter<<<NV1 / 256, 256, 0, stream>>>(pc, fgrid, idx0, idx1, (int*)base, out);

  // compaction chain (+ folded clears of idx2, idx3+idx4, h4)
  k_cscan<128, NV2, 0><<<NV0 / 4 / 256, 256, 0, stream>>>(
      idx0, list0, cnt, 0, idx1, idx2, (float*)nullptr);
  k_cscan<64, NV3 + NV4, 0><<<NV1 / 4 / 256, 256, 0, stream>>>(
      idx1, list1, cnt, 1, idx2, idx3, (float*)nullptr);
  k_cscan<32, 0, NV4 * 128><<<NV2 / 4 / 256, 256, 0, stream>>>(
      idx2, list2, cnt, 2, idx3, (unsigned short*)nullptr, h4);
  k_ctail<<<1, 256, 0, stream>>>(idx3, idx4, list3, list4, cnt);

  // submanifold conv (+ BN0 stats)
  k_subconv<<<(NPTS + 255) / 256, 256, 0, stream>>>(fgrid, list0, cnt, wsub, h0,
                                                    bnsum + 0, bnss + 0);

  // stage convs: BN-in fused, BN-out stats fused
  k_conv<8, 16, 16, 64, 0><<<dim3((NPTS + 127) / 128, 1), 256, 0, stream>>>(
      h0, idx0, list1, cnt, 0, 1, w0, bnsum + 0, bnss + 0, g0, b0,
      bnsum + 64, bnss + 64, h1);
  k_conv<16, 32, 32, 32, 0><<<dim3((NPTS + 63) / 64, 1), 256, 0, stream>>>(
      h1, idx1, list2, cnt, 1, 2, w1, bnsum + 64, bnss + 64, g1, b1,
      bnsum + 128, bnss + 128, h2);
  k_conv<32, 64, 32, 16, 0><<<dim3((NV3 + 63) / 64, 2), 256, 0, stream>>>(
      h2, idx2, list3, cnt, 2, 3, w2, bnsum + 128, bnss + 128, g2, b2,
      bnsum + 192, bnss + 192, h3);
  k_conv<64, 128, 16, 8, 1><<<dim3((NV4 + 127) / 128, 8), 256, 0, stream>>>(
      h3, idx3, list4, cnt, 3, 4, w3, bnsum + 192, bnss + 192, g3, b3,
      (float*)nullptr, (float*)nullptr, h4);

  // pools + classifier
  k_pool1<<<(NB * 128 * 64) / 256, 256, 0, stream>>>(h4, idx4, h5, mask5);
  k_tail<<<1, 256, 0, stream>>>(h5, mask5, Wc, bc, out);
}

// Round 4
// 273.641 us; speedup vs baseline: 1.1606x; 1.1606x over previous
//
#include <hip/hip_runtime.h>
#include <math.h>

// Sparse implementation of the masked 3D CNN (B=2, S=128, N=60000 points).
// Levels: 0:128^3  1:64^3  2:32^3  3:16^3  4:8^3, then dense pools 4^3, 2^3.
// uint16 index grids (ids < 60000; 0xFFFF empty, 0xFFFE marked).
// Two-pass block-scan compaction (1 global atomic per block), BN stats fused
// into producers across 16 spread slots, BN-apply fused into consumer convs.

#define NPTS 60000
#define NB 2
#define NEGF -3.0e38f
#define EPSF 1.0e-4f
#define MARKV 0xFFFEu
#define EMPTYV 0xFFFFu
#define NSLOT 16

constexpr int NV0 = NB * 128 * 128 * 128;  // 4194304
constexpr int NV1 = NB * 64 * 64 * 64;     // 524288
constexpr int NV2 = NB * 32 * 32 * 32;     // 65536
constexpr int NV3 = NB * 16 * 16 * 16;     // 8192
constexpr int NV4 = NB * 8 * 8 * 8;        // 1024

// ---- workspace layout (bytes) ----
constexpr size_t OFF_CNT   = 0;      // int[16]
constexpr size_t OFF_BNSUM = 1024;   // float[4][NSLOT][64] = 16 KB
constexpr size_t OFF_BNSS  = 17408;  // float[4][NSLOT][64] = 16 KB
constexpr size_t OFF_MASK5 = 33792;  // int[128]
constexpr size_t OFF_FGRID = 65536;                       // float[NV0]
constexpr size_t OFF_IDX0  = OFF_FGRID + (size_t)NV0 * 4; // u16[NV0]
constexpr size_t OFF_IDX1  = OFF_IDX0 + (size_t)NV0 * 2;
constexpr size_t OFF_IDX2  = OFF_IDX1 + (size_t)NV1 * 2;
constexpr size_t OFF_IDX3  = OFF_IDX2 + (size_t)NV2 * 2;
constexpr size_t OFF_IDX4  = OFF_IDX3 + (size_t)NV3 * 2;  // contiguous after idx3
constexpr size_t OFF_LIST0 = OFF_IDX4 + (size_t)NV4 * 2;
constexpr size_t OFF_LIST1 = OFF_LIST0 + (size_t)NPTS * 4;
constexpr size_t OFF_LIST2 = OFF_LIST1 + (size_t)NPTS * 4;
constexpr size_t OFF_LIST3 = OFF_LIST2 + (size_t)NPTS * 4;
constexpr size_t OFF_LIST4 = OFF_LIST3 + (size_t)NV3 * 4;
constexpr size_t OFF_H0 = OFF_LIST4 + (size_t)NV4 * 4;    // NPTS*8  f32
constexpr size_t OFF_H1 = OFF_H0 + (size_t)NPTS * 8 * 4;  // NPTS*16
constexpr size_t OFF_H2 = OFF_H1 + (size_t)NPTS * 16 * 4; // NPTS*32
constexpr size_t OFF_H3 = OFF_H2 + (size_t)NPTS * 32 * 4; // NV3*64
constexpr size_t OFF_H4 = OFF_H3 + (size_t)NV3 * 64 * 4;  // dense [b][128][8^3]
constexpr size_t OFF_H5 = OFF_H4 + (size_t)NV4 * 128 * 4; // [b][128][4^3]
constexpr size_t WS_END = OFF_H5 + (size_t)NB * 128 * 64 * 4;  // ~43.4 MB

// ---------------- kernels ----------------

// scatter points; also clears cnt+bn (33792 B) and idx1 (NV1 u16).
__global__ __launch_bounds__(256) void k_scatter(const float* __restrict__ pc,
                                                 float* __restrict__ fgrid,
                                                 unsigned short* __restrict__ idx0,
                                                 unsigned short* __restrict__ idx1,
                                                 int* __restrict__ wsw,
                                                 float* __restrict__ out) {
  int gid = blockIdx.x * 256 + threadIdx.x;  // grid = NV1 threads
  if (gid < 2112) {  // [0, 33792): cnt + bnsum + bnss
    ((int4*)wsw)[gid] = make_int4(0, 0, 0, 0);
  }
  if (gid < NV1 / 4) {
    ((ushort4*)idx1)[gid] =
        make_ushort4((unsigned short)EMPTYV, (unsigned short)EMPTYV,
                     (unsigned short)EMPTYV, (unsigned short)EMPTYV);
  }
  if (gid < NPTS) {
    const float* p = pc + (size_t)gid * 5;
    float fb = p[0], fx = p[1], fy = p[2], fz = p[3], f = p[4];
    ((float4*)out)[gid] = make_float4(fb, fx, fy, fz);
    int b = (int)fb, x = (int)fx, y = (int)fy, z = (int)fz;
    int v = ((b * 128 + x) * 128 + y) * 128 + z;
    atomicAdd(&fgrid[v], f);
    idx0[v] = (unsigned short)MARKV;  // benign multi-writer (same value)
  }
}

// Two-pass block-scan compaction. NBLK blocks x 256 threads; each thread
// register-caches IT ushort4s, counts marks, block-scans, ONE global atomic
// per block, then assigns ids from the register cache. Also marks parent
// level and optionally clears a u16 / f32 region (folded memsets).
template <int SL, int NBLK, int NCLR16, int NCLRF>
__global__ __launch_bounds__(256) void k_cscan(unsigned short* __restrict__ idx,
                                               int* __restrict__ list,
                                               int* __restrict__ cnt, int slot,
                                               unsigned short* __restrict__ idx_par,
                                               unsigned short* __restrict__ clr16,
                                               float* __restrict__ clrf) {
  constexpr int NV = NB * SL * SL * SL;
  constexpr int NT = NBLK * 256;
  constexpr int IT = NV / 4 / NT;  // ushort4 per thread
  int tid = threadIdx.x;
  int gid = blockIdx.x * 256 + tid;
  if (NCLR16 > 0) {
    ushort4 e4 = make_ushort4((unsigned short)EMPTYV, (unsigned short)EMPTYV,
                              (unsigned short)EMPTYV, (unsigned short)EMPTYV);
    for (int i = gid; i < NCLR16 / 4; i += NT) ((ushort4*)clr16)[i] = e4;
  }
  if (NCLRF > 0) {
    float4 z4 = make_float4(0.f, 0.f, 0.f, 0.f);
    for (int i = gid; i < NCLRF / 4; i += NT) ((float4*)clrf)[i] = z4;
  }
  const ushort4* idx4p = (const ushort4*)idx;
  ushort4 uu[IT];
  int c = 0;
#pragma unroll
  for (int it = 0; it < IT; it++) {
    uu[it] = idx4p[gid + it * NT];
    c += (uu[it].x == MARKV) + (uu[it].y == MARKV) + (uu[it].z == MARKV) +
         (uu[it].w == MARKV);
  }
  int lane = tid & 63, wid = tid >> 6;
  int x = c;
#pragma unroll
  for (int off = 1; off < 64; off <<= 1) {  // inclusive wave scan
    int y = __shfl_up(x, off, 64);
    if (lane >= off) x += y;
  }
  __shared__ int sw[4];
  __shared__ int sbase;
  if (lane == 63) sw[wid] = x;
  __syncthreads();
  if (tid == 0) {
    int r = 0;
#pragma unroll
    for (int w = 0; w < 4; w++) { int t = sw[w]; sw[w] = r; r += t; }
    sbase = r ? atomicAdd(&cnt[slot], r) : 0;
  }
  __syncthreads();
  if (!c) return;
  int my = sbase + sw[wid] + (x - c);
#pragma unroll
  for (int it = 0; it < IT; it++) {
    unsigned short us[4] = {uu[it].x, uu[it].y, uu[it].z, uu[it].w};
    int v0 = (gid + it * NT) * 4;
#pragma unroll
    for (int j = 0; j < 4; j++) {
      if (us[j] == MARKV) {
        int v = v0 + j;
        idx[v] = (unsigned short)my;
        list[my] = v;
        my++;
        int z = v & (SL - 1), y = (v / SL) & (SL - 1),
            xx = (v / (SL * SL)) & (SL - 1), b = v / (SL * SL * SL);
        constexpr int SP = SL / 2;
        int pv = ((b * SP + (xx >> 1)) * SP + (y >> 1)) * SP + (z >> 1);
        idx_par[pv] = (unsigned short)MARKV;
      }
    }
  }
}

// levels 3 and 4 compaction in one single-block kernel.
__global__ __launch_bounds__(256) void k_ctail(unsigned short* __restrict__ idx3,
                                               unsigned short* __restrict__ idx4,
                                               int* __restrict__ list3,
                                               int* __restrict__ list4,
                                               int* __restrict__ cnt) {
  __shared__ int lc3, lc4;
  int tid = threadIdx.x, lane = tid & 63;
  if (tid == 0) { lc3 = 0; lc4 = 0; }
  __syncthreads();
  for (int v = tid; v < NV3; v += 256) {
    bool p = (idx3[v] == MARKV);
    unsigned long long m = __ballot(p);
    int wb = 0;
    if (lane == 0 && m) wb = atomicAdd(&lc3, __popcll(m));
    wb = __shfl(wb, 0, 64);
    if (p) {
      int id = wb + __popcll(m & ((1ull << lane) - 1));
      idx3[v] = (unsigned short)id;
      list3[id] = v;
      int z = v & 15, y = (v >> 4) & 15, x = (v >> 8) & 15, b = v >> 12;
      int pv = ((b * 8 + (x >> 1)) * 8 + (y >> 1)) * 8 + (z >> 1);
      idx4[pv] = (unsigned short)MARKV;
    }
  }
  __syncthreads();  // idx4 marks visible block-wide
  for (int v = tid; v < NV4; v += 256) {
    bool p = (idx4[v] == MARKV);
    unsigned long long m = __ballot(p);
    int wb = 0;
    if (lane == 0 && m) wb = atomicAdd(&lc4, __popcll(m));
    wb = __shfl(wb, 0, 64);
    if (p) {
      int id = wb + __popcll(m & ((1ull << lane) - 1));
      idx4[v] = (unsigned short)id;
      list4[id] = v;
    }
  }
  __syncthreads();
  if (tid == 0) { cnt[3] = lc3; cnt[4] = lc4; }
}

// 3^3 SAME conv 1->8 at occupied voxels, 4 threads per point (7 taps each),
// shfl_xor combine; fused BN0 stat accumulation (slot-spread).
__global__ __launch_bounds__(256) void k_subconv(const float* __restrict__ fgrid,
                                                 const int* __restrict__ list0,
                                                 const int* __restrict__ cnt,
                                                 const float* __restrict__ wsub,
                                                 float* __restrict__ h0,
                                                 float* __restrict__ bnsum,
                                                 float* __restrict__ bnss) {
  int n = cnt[0];
  if ((int)(blockIdx.x * 64) >= n) return;  // uniform: 64 points per block
  __shared__ float wl[216];
  __shared__ float sbn[16];
  int tid = threadIdx.x;
  for (int i = tid; i < 216; i += 256) wl[i] = wsub[i];
  if (tid < 16) sbn[tid] = 0.f;
  __syncthreads();
  int pid = blockIdx.x * 64 + (tid >> 2);
  int sub = tid & 3;
  bool act = pid < n;
  float acc[8] = {0, 0, 0, 0, 0, 0, 0, 0};
  if (act) {
    int v = list0[pid];
    int z = v & 127, y = (v >> 7) & 127, x = (v >> 14) & 127, b = v >> 21;
    int t0 = sub * 7, t1 = t0 + 7 > 27 ? 27 : t0 + 7;
    for (int t = t0; t < t1; t++) {
      int kd = t / 9, kh = (t / 3) % 3, kw = t % 3;
      int xx = x + kd - 1, yy = y + kh - 1, zz = z + kw - 1;
      if ((unsigned)xx < 128u && (unsigned)yy < 128u && (unsigned)zz < 128u) {
        float val = fgrid[((b * 128 + xx) * 128 + yy) * 128 + zz];
        if (val != 0.f) {
#pragma unroll
          for (int o = 0; o < 8; o++) acc[o] = fmaf(val, wl[o * 27 + t], acc[o]);
        }
      }
    }
  }
#pragma unroll
  for (int o = 0; o < 8; o++) {  // combine the 4 tap-groups
    acc[o] += __shfl_xor(acc[o], 1, 64);
    acc[o] += __shfl_xor(acc[o], 2, 64);
  }
  if (act) {  // lane `sub` writes channels [2sub, 2sub+2) -> coalesced
    ((float2*)(h0 + (size_t)pid * 8))[sub] = make_float2(acc[sub * 2], acc[sub * 2 + 1]);
  }
  int lane = tid & 63;
#pragma unroll
  for (int o = 0; o < 8; o++) {  // each point counted once per channel
    float a = ((o >> 1) == sub && act) ? acc[o] : 0.f;
    float q = a * a;
#pragma unroll
    for (int off = 32; off > 0; off >>= 1) {
      a += __shfl_down(a, off, 64);
      q += __shfl_down(q, off, 64);
    }
    if (lane == 0) { atomicAdd(&sbn[o], a); atomicAdd(&sbn[8 + o], q); }
  }
  __syncthreads();
  if (tid < 8) {
    int s = (blockIdx.x & (NSLOT - 1)) * 64;
    atomicAdd(&bnsum[s + tid], sbn[tid]);
    atomicAdd(&bnss[s + tid], sbn[8 + tid]);
  }
}

// stride-2 VALID 2^3 conv. BN+ReLU applied to inputs (scale/bias derived
// in-block from slot-spread stats); output BN stats accumulated unless DENSE_OUT.
template <int Ci, int Co, int OCCHUNK, int SLpar, int DENSE_OUT>
__global__ __launch_bounds__(256) void k_conv(const float* __restrict__ hin,
                                              const unsigned short* __restrict__ idxc,
                                              const int* __restrict__ listpar,
                                              const int* __restrict__ cnt,
                                              int slot_bn, int slot_par,
                                              const float* __restrict__ w,
                                              const float* __restrict__ bnsum_in,
                                              const float* __restrict__ bnss_in,
                                              const float* __restrict__ g,
                                              const float* __restrict__ beta,
                                              float* __restrict__ bnsum_out,
                                              float* __restrict__ bnss_out,
                                              float* __restrict__ hout) {
  constexpr int TPP = OCCHUNK / 8;   // threads per parent
  constexpr int PPB = 256 / TPP;     // parents per block
  int n = cnt[slot_par];
  if ((int)(blockIdx.x * PPB) >= n) return;  // uniform
  __shared__ float wl[Ci * 8 * OCCHUNK];     // <= 32 KB for all stages
  __shared__ float sl[Ci], bl[Ci];
  __shared__ float bnl[2 * OCCHUNK];
  int tid = threadIdx.x;
  int ocbase = blockIdx.y * OCCHUNK;
  for (int i = tid; i < Ci * 8 * OCCHUNK; i += 256) {
    int ol = i % OCCHUNK;
    int it = i / OCCHUNK;  // ci*8 + t
    int ci = it >> 3, t = it & 7;
    wl[i] = w[((size_t)(ocbase + ol) * Ci + ci) * 8 + t];
  }
  if (tid < Ci) {
    float nn = (float)cnt[slot_bn];
    float s = 0.f, ss = 0.f;
#pragma unroll
    for (int k = 0; k < NSLOT; k++) { s += bnsum_in[k * 64 + tid]; ss += bnss_in[k * 64 + tid]; }
    float mu = s / nn;
    float var = fmaxf(ss / nn - mu * mu, 0.f);
    float sc = g[tid] / sqrtf(var + EPSF);
    sl[tid] = sc;
    bl[tid] = beta[tid] - mu * sc;
  }
  if (!DENSE_OUT && tid < 2 * OCCHUNK) bnl[tid] = 0.f;
  __syncthreads();
  int pid = blockIdx.x * PPB + tid / TPP;
  int og = tid % TPP;
  bool act = pid < n;
  float acc[8] = {0, 0, 0, 0, 0, 0, 0, 0};
  int Xc = 0, Yc = 0, Zc = 0, bb = 0;
  if (act) {
    int pv = listpar[pid];
    constexpr int SL = SLpar, SC = SLpar * 2;
    Zc = pv & (SL - 1);
    Yc = (pv / SL) & (SL - 1);
    Xc = (pv / (SL * SL)) & (SL - 1);
    bb = pv / (SL * SL * SL);
    for (int t = 0; t < 8; t++) {
      int kd = t >> 2, kh = (t >> 1) & 1, kw = t & 1;
      int cv = ((bb * SC + 2 * Xc + kd) * SC + 2 * Yc + kh) * SC + 2 * Zc + kw;
      unsigned e = idxc[cv];
      if (e >= 0xFFFEu) continue;  // empty child contributes 0
      const float* hp = hin + (size_t)e * Ci;
#pragma unroll
      for (int i = 0; i < Ci; i += 4) {
        float4 xv = *(const float4*)(hp + i);
        float y0 = fmaxf(fmaf(xv.x, sl[i + 0], bl[i + 0]), 0.f);
        float y1 = fmaxf(fmaf(xv.y, sl[i + 1], bl[i + 1]), 0.f);
        float y2 = fmaxf(fmaf(xv.z, sl[i + 2], bl[i + 2]), 0.f);
        float y3 = fmaxf(fmaf(xv.w, sl[i + 3], bl[i + 3]), 0.f);
        const float* wp0 = &wl[((i + 0) * 8 + t) * OCCHUNK + og * 8];
        const float* wp1 = &wl[((i + 1) * 8 + t) * OCCHUNK + og * 8];
        const float* wp2 = &wl[((i + 2) * 8 + t) * OCCHUNK + og * 8];
        const float* wp3 = &wl[((i + 3) * 8 + t) * OCCHUNK + og * 8];
#pragma unroll
        for (int o = 0; o < 8; o++) {
          acc[o] = fmaf(y0, wp0[o], acc[o]);
          acc[o] = fmaf(y1, wp1[o], acc[o]);
          acc[o] = fmaf(y2, wp2[o], acc[o]);
          acc[o] = fmaf(y3, wp3[o], acc[o]);
        }
      }
    }
    if (!DENSE_OUT) {
      float* op = hout + (size_t)pid * Co + ocbase + og * 8;
#pragma unroll
      for (int o = 0; o < 8; o++) op[o] = acc[o];
    } else {
      int sp = (Xc * 8 + Yc) * 8 + Zc;  // SLpar == 8
#pragma unroll
      for (int o = 0; o < 8; o++)
        hout[((size_t)bb * 128 + ocbase + og * 8 + o) * 512 + sp] = acc[o];
    }
  }
  if (!DENSE_OUT) {
    int lane = tid & 63;
#pragma unroll
    for (int o = 0; o < 8; o++) {
      float a = acc[o], q = a * a;
#pragma unroll
      for (int off = TPP; off < 64; off <<= 1) {
        a += __shfl_down(a, off, 64);
        q += __shfl_down(q, off, 64);
      }
      if (lane < TPP) {  // og == lane here
        atomicAdd(&bnl[lane * 8 + o], a);
        atomicAdd(&bnl[OCCHUNK + lane * 8 + o], q);
      }
    }
    __syncthreads();
    if (tid < OCCHUNK) {
      int s = (blockIdx.x & (NSLOT - 1)) * 64;
      atomicAdd(&bnsum_out[s + ocbase + tid], bnl[tid]);
      atomicAdd(&bnss_out[s + ocbase + tid], bnl[OCCHUNK + tid]);
    }
  }
}

// masked max-pool 8^3 -> 4^3 (dense), emits mask5.
__global__ __launch_bounds__(256) void k_pool1(const float* __restrict__ h4,
                                               const unsigned short* __restrict__ idx4,
                                               float* __restrict__ h5,
                                               int* __restrict__ mask5) {
  int tid = blockIdx.x * 256 + threadIdx.x;  // exactly NB*128*64 threads
  int sp = tid & 63;
  int c = (tid >> 6) & 127;
  int b = tid >> 13;
  int Z = sp & 3, Y = (sp >> 2) & 3, X = sp >> 4;
  float m = NEGF;
  int any = 0;
#pragma unroll
  for (int t = 0; t < 8; t++) {
    int kd = t >> 2, kh = (t >> 1) & 1, kw = t & 1;
    int csp = ((2 * X + kd) * 8 + 2 * Y + kh) * 8 + 2 * Z + kw;
    if (idx4[b * 512 + csp] != EMPTYV) {
      any = 1;
      m = fmaxf(m, h4[((size_t)b * 128 + c) * 512 + csp]);
    }
  }
  h5[((size_t)b * 128 + c) * 64 + sp] = any ? m : 0.f;
  if (c == 0) mask5[b * 64 + sp] = any;
}

// fused: masked max-pool 4^3 -> 2^3 + ReLU + (2x1024) linear classifier.
__global__ __launch_bounds__(256) void k_tail(const float* __restrict__ h5,
                                              const int* __restrict__ mask5,
                                              const float* __restrict__ Wc,
                                              const float* __restrict__ bcv,
                                              float* __restrict__ out) {
  __shared__ float h6s[2048];
  int tid = threadIdx.x;
#pragma unroll
  for (int j = 0; j < 8; j++) {
    int e = tid * 8 + j;  // e = b*1024 + c*8 + sp
    int sp = e & 7, c = (e >> 3) & 127, b = e >> 10;
    int Z = sp & 1, Y = (sp >> 1) & 1, X = sp >> 2;
    float m = NEGF;
    int any = 0;
#pragma unroll
    for (int t = 0; t < 8; t++) {
      int kd = t >> 2, kh = (t >> 1) & 1, kw = t & 1;
      int csp = ((2 * X + kd) * 4 + 2 * Y + kh) * 4 + 2 * Z + kw;
      if (mask5[b * 64 + csp]) {
        any = 1;
        m = fmaxf(m, h5[((size_t)b * 128 + c) * 64 + csp]);
      }
    }
    h6s[e] = any ? fmaxf(m, 0.f) : 0.f;  // classifier ReLU folded in
  }
  __syncthreads();
  int wave = tid >> 6, lane = tid & 63;
  int b = wave >> 1, o = wave & 1;
  float s = 0.f;
  for (int k = lane; k < 1024; k += 64) s += h6s[b * 1024 + k] * Wc[o * 1024 + k];
#pragma unroll
  for (int off = 32; off > 0; off >>= 1) s += __shfl_down(s, off, 64);
  if (lane == 0) out[240000 + b * 2 + o] = s + bcv[o];
}

// ---------------- host ----------------

extern "C" void kernel_launch(void* const* d_in, const int* in_sizes, int n_in,
                              void* d_out, int out_size, void* d_ws, size_t ws_size,
                              hipStream_t stream) {
  const float* pc   = (const float*)d_in[0];
  const float* wsub = (const float*)d_in[1];
  const float* w0   = (const float*)d_in[2];
  const float* w1   = (const float*)d_in[3];
  const float* w2   = (const float*)d_in[4];
  const float* w3   = (const float*)d_in[5];
  const float* g0   = (const float*)d_in[6];
  const float* g1   = (const float*)d_in[7];
  const float* g2   = (const float*)d_in[8];
  const float* g3   = (const float*)d_in[9];
  const float* b0   = (const float*)d_in[10];
  const float* b1   = (const float*)d_in[11];
  const float* b2   = (const float*)d_in[12];
  const float* b3   = (const float*)d_in[13];
  const float* Wc   = (const float*)d_in[14];
  const float* bc   = (const float*)d_in[15];
  float* out = (float*)d_out;

  char* base = (char*)d_ws;
  int*   cnt   = (int*)(base + OFF_CNT);
  float* bnsum = (float*)(base + OFF_BNSUM);  // [4][NSLOT][64]
  float* bnss  = (float*)(base + OFF_BNSS);
  int*   mask5 = (int*)(base + OFF_MASK5);
  float* fgrid = (float*)(base + OFF_FGRID);
  unsigned short* idx0 = (unsigned short*)(base + OFF_IDX0);
  unsigned short* idx1 = (unsigned short*)(base + OFF_IDX1);
  unsigned short* idx2 = (unsigned short*)(base + OFF_IDX2);
  unsigned short* idx3 = (unsigned short*)(base + OFF_IDX3);
  unsigned short* idx4 = (unsigned short*)(base + OFF_IDX4);
  int* list0 = (int*)(base + OFF_LIST0);
  int* list1 = (int*)(base + OFF_LIST1);
  int* list2 = (int*)(base + OFF_LIST2);
  int* list3 = (int*)(base + OFF_LIST3);
  int* list4 = (int*)(base + OFF_LIST4);
  float* h0 = (float*)(base + OFF_H0);
  float* h1 = (float*)(base + OFF_H1);
  float* h2 = (float*)(base + OFF_H2);
  float* h3 = (float*)(base + OFF_H3);
  float* h4 = (float*)(base + OFF_H4);
  float* h5 = (float*)(base + OFF_H5);

  hipMemsetAsync(fgrid, 0, (size_t)NV0 * 4, stream);
  hipMemsetAsync(idx0, 0xFF, (size_t)NV0 * 2, stream);

  // scatter (+ clear cnt/bn, idx1)
  k_scatter<<<NV1 / 256, 256, 0, stream>>>(pc, fgrid, idx0, idx1, (int*)base, out);

  // compaction chain (+ folded clears of idx2, idx3+idx4, h4)
  k_cscan<128, 128, NV2, 0><<<128, 256, 0, stream>>>(
      idx0, list0, cnt, 0, idx1, idx2, (float*)nullptr);
  k_cscan<64, 64, NV3 + NV4, 0><<<64, 256, 0, stream>>>(
      idx1, list1, cnt, 1, idx2, idx3, (float*)nullptr);
  k_cscan<32, 16, 0, NV4 * 128><<<16, 256, 0, stream>>>(
      idx2, list2, cnt, 2, idx3, (unsigned short*)nullptr, h4);
  k_ctail<<<1, 256, 0, stream>>>(idx3, idx4, list3, list4, cnt);

  // submanifold conv (+ BN0 stats), 4 threads/point
  k_subconv<<<(NPTS * 4 + 255) / 256, 256, 0, stream>>>(fgrid, list0, cnt, wsub,
                                                        h0, bnsum, bnss);

  // stage convs: BN-in fused, BN-out stats fused (slot-spread)
  k_conv<8, 16, 16, 64, 0><<<dim3((NPTS + 127) / 128, 1), 256, 0, stream>>>(
      h0, idx0, list1, cnt, 0, 1, w0, bnsum, bnss, g0, b0,
      bnsum + 1024, bnss + 1024, h1);
  k_conv<16, 32, 32, 32, 0><<<dim3((NPTS + 63) / 64, 1), 256, 0, stream>>>(
      h1, idx1, list2, cnt, 1, 2, w1, bnsum + 1024, bnss + 1024, g1, b1,
      bnsum + 2048, bnss + 2048, h2);
  k_conv<32, 64, 32, 16, 0><<<dim3((NV3 + 63) / 64, 2), 256, 0, stream>>>(
      h2, idx2, list3, cnt, 2, 3, w2, bnsum + 2048, bnss + 2048, g2, b2,
      bnsum + 3072, bnss + 3072, h3);
  k_conv<64, 128, 16, 8, 1><<<dim3((NV4 + 127) / 128, 8), 256, 0, stream>>>(
      h3, idx3, list4, cnt, 3, 4, w3, bnsum + 3072, bnss + 3072, g3, b3,
      (float*)nullptr, (float*)nullptr, h4);

  // pools + classifier
  k_pool1<<<(NB * 128 * 64) / 256, 256, 0, stream>>>(h4, idx4, h5, mask5);
  k_tail<<<1, 256, 0, stream>>>(h5, mask5, Wc, bc, out);
}